// Round 12
// baseline (214.628 us; speedup 1.0000x reference)
//
#include <hip/hip_runtime.h>
#include <hip/hip_bf16.h>
#include <cstdint>

#define B_ 4
#define SQ_ 128
#define SKV_ 8192
#define H_ 32
#define D_ 128
#define KT 32
#define HD (H_ * D_)
#define NSPLIT 4

typedef __bf16 bf16x8 __attribute__((ext_vector_type(8)));
typedef float f32x4 __attribute__((ext_vector_type(4)));

union U4B8 { uint4 u; bf16x8 v; };

__device__ inline unsigned f2b_pack(float a, float b){
  unsigned ua = __float_as_uint(a); ua = (ua + 0x7FFFu + ((ua >> 16) & 1u)) >> 16;
  unsigned ub = __float_as_uint(b); ub = (ub + 0x7FFFu + ((ub >> 16) & 1u)) >> 16;
  return (ua & 0xFFFFu) | (ub << 16);
}
__device__ inline unsigned short f2b1(float a){
  unsigned ua = __float_as_uint(a);
  return (unsigned short)((ua + 0x7FFFu + ((ua >> 16) & 1u)) >> 16);
}

__global__ void mha_zero_cnt(unsigned* cnt) { cnt[threadIdx.x] = 0; }

// Split-KV attention (R8-proven body) + FUSED split-K combine.
// Block = 512 threads = 8 waves; each wave owns 16 Q rows. KT=32 keys/tile.
// Register prefetch of tile t+1 overlaps HBM latency with tile t's compute.
// Epilogue: block writes U/l partials, then device-scope ACQ_REL atomicAdd on
// cnt[bh]; the 4th arriver combines that head inline (overlaps other heads'
// streaming; kills the serial combine tail + one launch).
// LDS 40KB: K dbuf 2x8K + V^T dbuf 2x8K + P 8K (1K/wave).
// launch_bounds(512,4): R8-proven (64 arch VGPR + 32 acc, no spill),
// 2 blocks/CU x 8 waves = 16 waves/CU, grid 512 fully resident.
__global__ __launch_bounds__(512, 4) void mha_split_kernel(
    const float* __restrict__ q, const float* __restrict__ k, const float* __restrict__ v,
    float* __restrict__ Ubase, float* __restrict__ Lbase, unsigned* __restrict__ cnt,
    float* __restrict__ outp)
{
  __shared__ char smem[40 * 1024] __attribute__((aligned(16)));
  // K0 @0, K1 @8K: [32 keys][128 d] bf16, 256B rows, slot swz ^((key&7)<<4)
  // V0 @16K, V1 @24K: V^T [128 d][32 keys] bf16, 64B rows, slot swz ^((d>>2)&3)
  // P  @32K: per-wave [16 rows][32 cols] bf16, 64B rows, slot swz ^((row>>2)&3)

  const int tid = threadIdx.x;
  const int w = tid >> 6;
  const int l = tid & 63;
  const int g = l >> 4;      // 16-lane group 0..3
  const int c = l & 15;      // lane within group
  char* Plds = smem + 32768 + w * 1024;

  const int bh = blockIdx.x;
  const int split = blockIdx.y;
  const int b = bh >> 5, h = bh & 31;
  const int kps = SKV_ / NSPLIT;
  const int kv0 = split * kps;
  const int nt = kps / KT;

  const float qscale = 0.08838834764831845f * 1.4426950408889634f; // 1/sqrt(128)*log2(e)

  // ---- Q fragments (A-operand: m=c, k = ks*32 + g*8 + j); wave rows w*16..+15
  bf16x8 qf[4];
  {
    const float* qr = q + (((size_t)b * SQ_ + (w * 16 + c)) * H_ + h) * D_;
#pragma unroll
    for (int ks = 0; ks < 4; ++ks) {
      int d0 = ks * 32 + g * 8;
      float4 x = *(const float4*)(qr + d0);
      float4 y = *(const float4*)(qr + d0 + 4);
      U4B8 t;
      t.u.x = f2b_pack(x.x * qscale, x.y * qscale);
      t.u.y = f2b_pack(x.z * qscale, x.w * qscale);
      t.u.z = f2b_pack(y.x * qscale, y.y * qscale);
      t.u.w = f2b_pack(y.z * qscale, y.w * qscale);
      qf[ks] = t.v;
    }
  }

  f32x4 oacc[8];
#pragma unroll
  for (int ni = 0; ni < 8; ++ni) oacc[ni] = (f32x4)0.0f;
  float lacc[4] = {};

  const float* kbase = k + ((size_t)b * SKV_ + kv0) * HD + (size_t)h * D_;
  const float* vbase = v + ((size_t)b * SKV_ + kv0) * HD + (size_t)h * D_;

  // staging assignments (512 threads, 32-key tile)
  const int key_s = tid >> 4;          // 0..31  (K: one key row, 8 floats)
  const int d8_s  = (tid & 15) * 8;    // K: d offset
  const int kp_s  = tid >> 5;          // 0..15  (V: key pair)
  const int d4_s  = (tid & 31) * 4;    // V: d offset
  const int koff_w = key_s * 256 + ((d8_s * 2) ^ ((key_s & 7) << 4));

  float4 kreg0, kreg1, vreg0, vreg1;

  // ---- prologue: stage tile 0 into buf 0
  {
    const float* kt = kbase + (size_t)key_s * HD + d8_s;
    kreg0 = *(const float4*)(kt);
    kreg1 = *(const float4*)(kt + 4);
    const float* vt = vbase + (size_t)(kp_s * 2) * HD + d4_s;
    vreg0 = *(const float4*)(vt);
    vreg1 = *(const float4*)(vt + HD);
    uint4 kw;
    kw.x = f2b_pack(kreg0.x, kreg0.y); kw.y = f2b_pack(kreg0.z, kreg0.w);
    kw.z = f2b_pack(kreg1.x, kreg1.y); kw.w = f2b_pack(kreg1.z, kreg1.w);
    *(uint4*)(smem + koff_w) = kw;
    float va[4] = {vreg0.x, vreg0.y, vreg0.z, vreg0.w};
    float vb[4] = {vreg1.x, vreg1.y, vreg1.z, vreg1.w};
#pragma unroll
    for (int i = 0; i < 4; ++i) {
      int d = d4_s + i;
      int slot = ((kp_s >> 2) ^ ((d >> 2) & 3)) & 3;
      *(unsigned*)(smem + 16384 + d * 64 + slot * 16 + (kp_s & 3) * 4) = f2b_pack(va[i], vb[i]);
    }
  }
  __syncthreads();

  for (int t = 0; t < nt; ++t) {
    const int cur = t & 1;
    char* kc = smem + cur * 8192;
    char* vc = smem + 16384 + cur * 8192;

    // ---- issue prefetch loads for tile t+1 (held in regs through compute)
    if (t + 1 < nt) {
      const float* kt = kbase + (size_t)(t + 1) * KT * HD + (size_t)key_s * HD + d8_s;
      kreg0 = *(const float4*)(kt);
      kreg1 = *(const float4*)(kt + 4);
      const float* vt = vbase + (size_t)(t + 1) * KT * HD + (size_t)(kp_s * 2) * HD + d4_s;
      vreg0 = *(const float4*)(vt);
      vreg1 = *(const float4*)(vt + HD);
    }
    __builtin_amdgcn_sched_barrier(0);  // pin loads above the compute

    __builtin_amdgcn_s_setprio(1);
    // ---- S = Q K^T (16 rows x 32 keys: 8 MFMA)
    f32x4 sacc[2];
#pragma unroll
    for (int ni = 0; ni < 2; ++ni) sacc[ni] = (f32x4)0.0f;
#pragma unroll
    for (int ni = 0; ni < 2; ++ni) {
      int key = ni * 16 + c;
      int rb = key * 256;
      int sw = (key & 7) << 4;
#pragma unroll
      for (int ks = 0; ks < 4; ++ks) {
        U4B8 bf;
        bf.u = *(uint4*)(kc + rb + ((ks * 64 + g * 16) ^ sw));
        sacc[ni] = __builtin_amdgcn_mfma_f32_16x16x32_bf16(qf[ks], bf.v, sacc[ni], 0, 0, 0);
      }
    }

    // ---- p = exp2(s) -> P (wave-private; in-wave lgkm ordering, no barrier)
#pragma unroll
    for (int ni = 0; ni < 2; ++ni) {
#pragma unroll
      for (int r = 0; r < 4; ++r) {
        float p = exp2f(sacc[ni][r]);
        lacc[r] += p;
        int row = g * 4 + r;
        int col = ni * 16 + c;
        int off = row * 64 + ((((col >> 3) ^ g) & 3) * 16) + (col & 7) * 2;
        *(unsigned short*)(Plds + off) = f2b1(p);
      }
    }

    // ---- O += P V (one K=32 step x 8 d-blocks)
    {
      const int slot = ((g ^ (c >> 2)) & 3) * 16;
      U4B8 ap;
      ap.u = *(uint4*)(Plds + c * 64 + slot);
#pragma unroll
      for (int ni = 0; ni < 8; ++ni) {
        int d = ni * 16 + c;
        U4B8 bv;
        bv.u = *(uint4*)(vc + d * 64 + slot);
        oacc[ni] = __builtin_amdgcn_mfma_f32_16x16x32_bf16(ap.v, bv.v, oacc[ni], 0, 0, 0);
      }
    }
    __builtin_amdgcn_s_setprio(0);

    // ---- convert + write prefetched tile into buf[cur^1] (vmcnt wait lands here)
    if (t + 1 < nt) {
      char* kn = smem + (cur ^ 1) * 8192;
      char* vn = smem + 16384 + (cur ^ 1) * 8192;
      uint4 kw;
      kw.x = f2b_pack(kreg0.x, kreg0.y); kw.y = f2b_pack(kreg0.z, kreg0.w);
      kw.z = f2b_pack(kreg1.x, kreg1.y); kw.w = f2b_pack(kreg1.z, kreg1.w);
      *(uint4*)(kn + koff_w) = kw;
      float va[4] = {vreg0.x, vreg0.y, vreg0.z, vreg0.w};
      float vb[4] = {vreg1.x, vreg1.y, vreg1.z, vreg1.w};
#pragma unroll
      for (int i = 0; i < 4; ++i) {
        int d = d4_s + i;
        int slot = ((kp_s >> 2) ^ ((d >> 2) & 3)) & 3;
        *(unsigned*)(vn + d * 64 + slot * 16 + (kp_s & 3) * 4) = f2b_pack(va[i], vb[i]);
      }
    }
    __syncthreads();   // staged writes visible; all reads of buf[cur] done
  }

  // ---- reduce l across the 16 lanes sharing each row
#pragma unroll
  for (int r = 0; r < 4; ++r) {
    float s = lacc[r];
    s += __shfl_xor(s, 1, 16);
    s += __shfl_xor(s, 2, 16);
    s += __shfl_xor(s, 4, 16);
    s += __shfl_xor(s, 8, 16);
    lacc[r] = s;
  }

  // ---- write U/l partials for this (bh, split)
  {
    float* Up = Ubase + ((size_t)split * 128 + bh) * (SQ_ * D_);
#pragma unroll
    for (int r = 0; r < 4; ++r) {
      int row = w * 16 + g * 4 + r;
#pragma unroll
      for (int ni = 0; ni < 8; ++ni) {
        Up[(size_t)row * D_ + ni * 16 + c] = oacc[ni][r];
      }
      if (c == 0) Lbase[((size_t)split * 128 + bh) * SQ_ + row] = lacc[r];
    }
  }
  __syncthreads();

  // ---- arrival: 4th block for this bh performs the combine inline
  volatile unsigned* flag = (volatile unsigned*)smem;
  if (tid == 0) {
    unsigned old = __hip_atomic_fetch_add(&cnt[bh], 1u, __ATOMIC_ACQ_REL,
                                          __HIP_MEMORY_SCOPE_AGENT);
    *flag = (old == NSPLIT - 1) ? 1u : 0u;
  }
  __syncthreads();
  if (*flag == 0) return;

  // cache l-sums for the 128 rows in LDS
  float* lsum = (float*)(smem + 64);
  if (tid < 128) {
    float s = 0.f;
#pragma unroll
    for (int sp = 0; sp < NSPLIT; ++sp)
      s += Lbase[((size_t)sp * 128 + bh) * SQ_ + tid];
    lsum[tid] = 1.0f / s;
  }
  __syncthreads();

  // combine 16384 floats (4096 float4) with 512 threads
  {
    const float4* U0 = (const float4*)(Ubase + ((size_t)0 * 128 + bh) * (SQ_ * D_));
    const float4* U1 = (const float4*)(Ubase + ((size_t)1 * 128 + bh) * (SQ_ * D_));
    const float4* U2 = (const float4*)(Ubase + ((size_t)2 * 128 + bh) * (SQ_ * D_));
    const float4* U3 = (const float4*)(Ubase + ((size_t)3 * 128 + bh) * (SQ_ * D_));
#pragma unroll
    for (int it = 0; it < 8; ++it) {
      int i = it * 512 + tid;          // float4 index; row = i >> 5
      int row = i >> 5;
      float4 a = U0[i], b4 = U1[i], c4 = U2[i], d4 = U3[i];
      float inv = lsum[row];
      float4 o;
      o.x = (a.x + b4.x + c4.x + d4.x) * inv;
      o.y = (a.y + b4.y + c4.y + d4.y) * inv;
      o.z = (a.z + b4.z + c4.z + d4.z) * inv;
      o.w = (a.w + b4.w + c4.w + d4.w) * inv;
      int dcol = (i & 31) * 4;
      *(float4*)(outp + (((size_t)b * SQ_ + row) * H_ + h) * D_ + dcol) = o;
    }
  }
}

extern "C" void kernel_launch(void* const* d_in, const int* in_sizes, int n_in,
                              void* d_out, int out_size, void* d_ws, size_t ws_size,
                              hipStream_t stream) {
  const float* q = (const float*)d_in[0];
  const float* k = (const float*)d_in[1];
  const float* v = (const float*)d_in[2];
  float* outp = (float*)d_out;

  float* Ubase = (float*)d_ws;                                    // 4*128*128*128 f32 = 33.5 MB
  float* Lbase = Ubase + (size_t)NSPLIT * 128 * SQ_ * D_;          // 4*128*128 f32
  unsigned* cnt = (unsigned*)(Lbase + (size_t)NSPLIT * 128 * SQ_); // 128 u32

  mha_zero_cnt<<<1, 128, 0, stream>>>(cnt);
  dim3 grid(128, NSPLIT);
  mha_split_kernel<<<grid, 512, 0, stream>>>(q, k, v, Ubase, Lbase, cnt, outp);
}

// Round 13
// 198.343 us; speedup vs baseline: 1.0821x; 1.0821x over previous
//
#include <hip/hip_runtime.h>
#include <hip/hip_bf16.h>
#include <cstdint>

#define B_ 4
#define SQ_ 128
#define SKV_ 8192
#define H_ 32
#define D_ 128
#define KT 32
#define HD (H_ * D_)

typedef __bf16 bf16x8 __attribute__((ext_vector_type(8)));
typedef float f32x4 __attribute__((ext_vector_type(4)));

union U4B8 { uint4 u; bf16x8 v; };

__device__ inline unsigned f2b_pack(float a, float b){
  unsigned ua = __float_as_uint(a); ua = (ua + 0x7FFFu + ((ua >> 16) & 1u)) >> 16;
  unsigned ub = __float_as_uint(b); ub = (ub + 0x7FFFu + ((ub >> 16) & 1u)) >> 16;
  return (ua & 0xFFFFu) | (ub << 16);
}
__device__ inline unsigned short f2b1(float a){
  unsigned ua = __float_as_uint(a);
  return (unsigned short)((ua + 0x7FFFu + ((ua >> 16) & 1u)) >> 16);
}

// Split-KV attention, register-carried double-buffer pipeline (R8, best: 197.6us).
// Block = 512 threads = 8 waves; each wave owns 16 Q rows. KT=32 keys/tile.
// Per iter t: issue global loads for tile t+1 (16 VGPRs, pinned by
// sched_barrier) -> compute tile t from LDS buf[cur] -> convert+write regs to
// buf[cur^1] (vmcnt wait lands here, covered by compute) -> ONE barrier.
// P is a dedicated per-wave LDS region: in-wave ds ordering makes write->read
// safe without a barrier. LDS: K dbuf 16K + V dbuf 16K + P 8K = 40 KB.
// launch_bounds(512,4): 64 arch VGPR + 32 acc, no spill -> 2 blocks x 8 waves
// = 16 waves/CU; grid 512 fully resident. Separate lean combine kernel
// (fusing it regressed: R12 agent-scope fence cost > 12us tail).
__global__ __launch_bounds__(512, 4) void mha_split_kernel(
    const float* __restrict__ q, const float* __restrict__ k, const float* __restrict__ v,
    float* __restrict__ Ubase, float* __restrict__ Lbase, float* __restrict__ outp, int nsplit)
{
  __shared__ char smem[40 * 1024] __attribute__((aligned(16)));
  // K0 @0, K1 @8K: [32 keys][128 d] bf16, 256B rows, slot swz ^((key&7)<<4)
  // V0 @16K, V1 @24K: V^T [128 d][32 keys] bf16, 64B rows, slot swz ^((d>>2)&3)
  // P  @32K: per-wave [16 rows][32 cols] bf16, 64B rows, slot swz ^((row>>2)&3)

  const int tid = threadIdx.x;
  const int w = tid >> 6;
  const int l = tid & 63;
  const int g = l >> 4;      // 16-lane group 0..3
  const int c = l & 15;      // lane within group
  char* Plds = smem + 32768 + w * 1024;

  const int bh = blockIdx.x;
  const int split = blockIdx.y;
  const int b = bh >> 5, h = bh & 31;
  const int kps = SKV_ / nsplit;
  const int kv0 = split * kps;
  const int nt = kps / KT;

  const float qscale = 0.08838834764831845f * 1.4426950408889634f; // 1/sqrt(128)*log2(e)

  // ---- Q fragments (A-operand: m=c, k = ks*32 + g*8 + j); wave rows w*16..w*16+15
  bf16x8 qf[4];
  {
    const float* qr = q + (((size_t)b * SQ_ + (w * 16 + c)) * H_ + h) * D_;
#pragma unroll
    for (int ks = 0; ks < 4; ++ks) {
      int d0 = ks * 32 + g * 8;
      float4 x = *(const float4*)(qr + d0);
      float4 y = *(const float4*)(qr + d0 + 4);
      U4B8 t;
      t.u.x = f2b_pack(x.x * qscale, x.y * qscale);
      t.u.y = f2b_pack(x.z * qscale, x.w * qscale);
      t.u.z = f2b_pack(y.x * qscale, y.y * qscale);
      t.u.w = f2b_pack(y.z * qscale, y.w * qscale);
      qf[ks] = t.v;
    }
  }

  f32x4 oacc[8];
#pragma unroll
  for (int ni = 0; ni < 8; ++ni) oacc[ni] = (f32x4)0.0f;
  float lacc[4] = {};

  const float* kbase = k + ((size_t)b * SKV_ + kv0) * HD + (size_t)h * D_;
  const float* vbase = v + ((size_t)b * SKV_ + kv0) * HD + (size_t)h * D_;

  // staging assignments (512 threads, 32-key tile)
  const int key_s = tid >> 4;          // 0..31  (K: one key row, 8 floats)
  const int d8_s  = (tid & 15) * 8;    // K: d offset
  const int kp_s  = tid >> 5;          // 0..15  (V: key pair, 4 d-values x 2 keys)
  const int d4_s  = (tid & 31) * 4;    // V: d offset
  const int koff_w = key_s * 256 + ((d8_s * 2) ^ ((key_s & 7) << 4));

  float4 kreg0, kreg1, vreg0, vreg1;

  // ---- prologue: stage tile 0 into buf 0
  {
    const float* kt = kbase + (size_t)key_s * HD + d8_s;
    kreg0 = *(const float4*)(kt);
    kreg1 = *(const float4*)(kt + 4);
    const float* vt = vbase + (size_t)(kp_s * 2) * HD + d4_s;
    vreg0 = *(const float4*)(vt);
    vreg1 = *(const float4*)(vt + HD);
    uint4 kw;
    kw.x = f2b_pack(kreg0.x, kreg0.y); kw.y = f2b_pack(kreg0.z, kreg0.w);
    kw.z = f2b_pack(kreg1.x, kreg1.y); kw.w = f2b_pack(kreg1.z, kreg1.w);
    *(uint4*)(smem + koff_w) = kw;
    float va[4] = {vreg0.x, vreg0.y, vreg0.z, vreg0.w};
    float vb[4] = {vreg1.x, vreg1.y, vreg1.z, vreg1.w};
#pragma unroll
    for (int i = 0; i < 4; ++i) {
      int d = d4_s + i;
      int slot = ((kp_s >> 2) ^ ((d >> 2) & 3)) & 3;
      *(unsigned*)(smem + 16384 + d * 64 + slot * 16 + (kp_s & 3) * 4) = f2b_pack(va[i], vb[i]);
    }
  }
  __syncthreads();

  for (int t = 0; t < nt; ++t) {
    const int cur = t & 1;
    char* kc = smem + cur * 8192;
    char* vc = smem + 16384 + cur * 8192;

    // ---- issue prefetch loads for tile t+1 (held in regs through compute)
    if (t + 1 < nt) {
      const float* kt = kbase + (size_t)(t + 1) * KT * HD + (size_t)key_s * HD + d8_s;
      kreg0 = *(const float4*)(kt);
      kreg1 = *(const float4*)(kt + 4);
      const float* vt = vbase + (size_t)(t + 1) * KT * HD + (size_t)(kp_s * 2) * HD + d4_s;
      vreg0 = *(const float4*)(vt);
      vreg1 = *(const float4*)(vt + HD);
    }
    __builtin_amdgcn_sched_barrier(0);  // pin loads above the compute

    __builtin_amdgcn_s_setprio(1);
    // ---- S = Q K^T (16 rows x 32 keys: 8 MFMA)
    f32x4 sacc[2];
#pragma unroll
    for (int ni = 0; ni < 2; ++ni) sacc[ni] = (f32x4)0.0f;
#pragma unroll
    for (int ni = 0; ni < 2; ++ni) {
      int key = ni * 16 + c;
      int rb = key * 256;
      int sw = (key & 7) << 4;
#pragma unroll
      for (int ks = 0; ks < 4; ++ks) {
        U4B8 bf;
        bf.u = *(uint4*)(kc + rb + ((ks * 64 + g * 16) ^ sw));
        sacc[ni] = __builtin_amdgcn_mfma_f32_16x16x32_bf16(qf[ks], bf.v, sacc[ni], 0, 0, 0);
      }
    }

    // ---- p = exp2(s) -> P (wave-private; in-wave lgkm ordering, no barrier)
#pragma unroll
    for (int ni = 0; ni < 2; ++ni) {
#pragma unroll
      for (int r = 0; r < 4; ++r) {
        float p = exp2f(sacc[ni][r]);
        lacc[r] += p;
        int row = g * 4 + r;
        int col = ni * 16 + c;
        int off = row * 64 + ((((col >> 3) ^ g) & 3) * 16) + (col & 7) * 2;
        *(unsigned short*)(Plds + off) = f2b1(p);
      }
    }

    // ---- O += P V (one K=32 step x 8 d-blocks)
    {
      const int slot = ((g ^ (c >> 2)) & 3) * 16;
      U4B8 ap;
      ap.u = *(uint4*)(Plds + c * 64 + slot);
#pragma unroll
      for (int ni = 0; ni < 8; ++ni) {
        int d = ni * 16 + c;
        U4B8 bv;
        bv.u = *(uint4*)(vc + d * 64 + slot);
        oacc[ni] = __builtin_amdgcn_mfma_f32_16x16x32_bf16(ap.v, bv.v, oacc[ni], 0, 0, 0);
      }
    }
    __builtin_amdgcn_s_setprio(0);

    // ---- convert + write prefetched tile into buf[cur^1] (vmcnt wait lands here)
    if (t + 1 < nt) {
      char* kn = smem + (cur ^ 1) * 8192;
      char* vn = smem + 16384 + (cur ^ 1) * 8192;
      uint4 kw;
      kw.x = f2b_pack(kreg0.x, kreg0.y); kw.y = f2b_pack(kreg0.z, kreg0.w);
      kw.z = f2b_pack(kreg1.x, kreg1.y); kw.w = f2b_pack(kreg1.z, kreg1.w);
      *(uint4*)(kn + koff_w) = kw;
      float va[4] = {vreg0.x, vreg0.y, vreg0.z, vreg0.w};
      float vb[4] = {vreg1.x, vreg1.y, vreg1.z, vreg1.w};
#pragma unroll
      for (int i = 0; i < 4; ++i) {
        int d = d4_s + i;
        int slot = ((kp_s >> 2) ^ ((d >> 2) & 3)) & 3;
        *(unsigned*)(vn + d * 64 + slot * 16 + (kp_s & 3) * 4) = f2b_pack(va[i], vb[i]);
      }
    }
    __syncthreads();   // staged writes visible; all reads of buf[cur] done
  }

  // ---- reduce l across the 16 lanes sharing each row
#pragma unroll
  for (int r = 0; r < 4; ++r) {
    float s = lacc[r];
    s += __shfl_xor(s, 1, 16);
    s += __shfl_xor(s, 2, 16);
    s += __shfl_xor(s, 4, 16);
    s += __shfl_xor(s, 8, 16);
    lacc[r] = s;
  }

  if (nsplit == 1) {
    float* op = outp + (((size_t)b * SQ_) * H_ + h) * D_;
#pragma unroll
    for (int r = 0; r < 4; ++r) {
      int row = w * 16 + g * 4 + r;
      float inv = 1.0f / lacc[r];
#pragma unroll
      for (int ni = 0; ni < 8; ++ni) {
        op[(size_t)row * HD + ni * 16 + c] = oacc[ni][r] * inv;
      }
    }
  } else {
    float* Up = Ubase + ((size_t)split * 128 + bh) * (SQ_ * D_);
#pragma unroll
    for (int r = 0; r < 4; ++r) {
      int row = w * 16 + g * 4 + r;
#pragma unroll
      for (int ni = 0; ni < 8; ++ni) {
        Up[(size_t)row * D_ + ni * 16 + c] = oacc[ni][r];
      }
      if (c == 0) Lbase[((size_t)split * 128 + bh) * SQ_ + row] = lacc[r];
    }
  }
}

// Combine kernel: out = sum_s U_s / sum_s l_s, layout [b,h,q,d] -> [b,q,h,d]
__global__ void mha_combine_kernel(const float* __restrict__ Ubase, const float* __restrict__ Lbase,
                                   float* __restrict__ outp, int nsplit) {
  int idx = blockIdx.x * 256 + threadIdx.x;   // over BH*SQ*D = 2M
  int rowlin = idx >> 7;                       // bh*128 + row
  int d = idx & 127;
  float su = 0.f, sl = 0.f;
  for (int s = 0; s < nsplit; ++s) {
    su += Ubase[(size_t)s * (128 * SQ_ * D_) + idx];
    sl += Lbase[(size_t)s * (128 * SQ_) + rowlin];
  }
  int bh = rowlin >> 7, row = rowlin & 127;
  int b = bh >> 5, h = bh & 31;
  outp[(((size_t)b * SQ_ + row) * H_ + h) * D_ + d] = su / sl;
}

extern "C" void kernel_launch(void* const* d_in, const int* in_sizes, int n_in,
                              void* d_out, int out_size, void* d_ws, size_t ws_size,
                              hipStream_t stream) {
  const float* q = (const float*)d_in[0];
  const float* k = (const float*)d_in[1];
  const float* v = (const float*)d_in[2];
  float* outp = (float*)d_out;

  const size_t per_split = (size_t)128 * SQ_ * D_ * 4 + (size_t)128 * SQ_ * 4; // U + l
  int nsplit = 1;
  if (ws_size >= 4 * per_split) nsplit = 4;       // 512 blocks of 512 thr = 2/CU resident
  else if (ws_size >= 2 * per_split) nsplit = 2;

  float* Ubase = (float*)d_ws;
  float* Lbase = Ubase + (size_t)nsplit * 128 * SQ_ * D_;

  dim3 grid(128, nsplit);
  mha_split_kernel<<<grid, 512, 0, stream>>>(q, k, v, Ubase, Lbase, outp, nsplit);
  if (nsplit > 1) {
    mha_combine_kernel<<<(128 * SQ_ * D_) / 256, 256, 0, stream>>>(Ubase, Lbase, outp, nsplit);
  }
}